// Round 1
// baseline (206.725 us; speedup 1.0000x reference)
//
#include <hip/hip_runtime.h>

#define L_  512
#define B_  4
#define E_  256
#define TT  16
#define TI  64

typedef unsigned short u16;

__device__ __forceinline__ u16 f2bf(float x) {
  unsigned u = __float_as_uint(x);
  unsigned r = (u + 0x7fffu + ((u >> 16) & 1u)) >> 16;
  return (u16)r;
}
__device__ __forceinline__ float bflo(unsigned u) { return __uint_as_float(u << 16); }
__device__ __forceinline__ float bfhi(unsigned u) { return __uint_as_float(u & 0xffff0000u); }

__device__ __forceinline__ float sigw(float x) {
  float e = __builtin_amdgcn_exp2f(x * -1.44269504f);
  return __builtin_amdgcn_rcpf(1.0f + e);
}

// ---------------- GEMM: O[r][f] = sum_e A[r][e] * W[f][e], r in [0,2048), f,e in [0,256)
__global__ __launch_bounds__(256) void gemm3_k(
    const float* __restrict__ A,
    const float* __restrict__ w1, const float* __restrict__ w2, const float* __restrict__ w3,
    float* __restrict__ o1, float* __restrict__ o2, float* __restrict__ o3) {
  __shared__ float As[64 * 32], Ws[64 * 32];
  const int tid = threadIdx.x, tx = tid & 15, ty = tid >> 4;
  const int r0 = blockIdx.x * 64, f0 = blockIdx.y * 64, z = blockIdx.z;
  const float* W = (z == 0) ? w1 : (z == 1) ? w2 : w3;
  float* O = (z == 0) ? o1 : (z == 1) ? o2 : o3;
  float acc[4][4] = {};
  for (int kb = 0; kb < 256; kb += 32) {
    for (int j = 0; j < 2; ++j) {
      int idx = j * 256 + tid;
      int r = idx >> 3, g = idx & 7;
      float4 av = *(const float4*)(A + (size_t)(r0 + r) * E_ + kb + g * 4);
      float4 wv = *(const float4*)(W + (size_t)(f0 + r) * E_ + kb + g * 4);
      int gs = g ^ ((r >> 2) & 7);
      *(float4*)(As + r * 32 + gs * 4) = av;
      *(float4*)(Ws + r * 32 + gs * 4) = wv;
    }
    __syncthreads();
#pragma unroll
    for (int g = 0; g < 8; ++g) {
      float4 a[4], w[4];
#pragma unroll
      for (int i = 0; i < 4; ++i) {
        int r = ty * 4 + i;
        a[i] = *(const float4*)(As + r * 32 + (g ^ ((r >> 2) & 7)) * 4);
        int f = tx * 4 + i;
        w[i] = *(const float4*)(Ws + f * 32 + (g ^ ((f >> 2) & 7)) * 4);
      }
#pragma unroll
      for (int i = 0; i < 4; ++i)
#pragma unroll
        for (int j = 0; j < 4; ++j)
          acc[i][j] += a[i].x * w[j].x + a[i].y * w[j].y + a[i].z * w[j].z + a[i].w * w[j].w;
    }
    __syncthreads();
  }
#pragma unroll
  for (int i = 0; i < 4; ++i) {
    float4 v = make_float4(acc[i][0], acc[i][1], acc[i][2], acc[i][3]);
    *(float4*)(O + (size_t)(r0 + ty * 4 + i) * E_ + f0 + tx * 4) = v;
  }
}

// ---------------- cumsum: qc[l,b,e] = q2[l,b,e] + b3[e] + sum_{j<=l} v3[j,b,e]  (in-place in v3qc)
__global__ __launch_bounds__(256) void cumsum_k(
    const float* __restrict__ q2, float* __restrict__ v3qc, const float* __restrict__ b3) {
  const int e = threadIdx.x, b = blockIdx.x;
  float run = 0.f;
  const float bb = b3[e];
  for (int l = 0; l < L_; ++l) {
    size_t o = ((size_t)l * B_ + b) * E_ + e;
    run += v3qc[o];
    v3qc[o] = q2[o] + bb + run;
  }
}

// ---------------- stage 64 rows x 256 cols fp32 -> bf16 LDS tile (pitch 264)
__device__ __forceinline__ void stage_tile_bf16(const float* __restrict__ src_base,
                                                u16* tile, int tid) {
  for (int c = 0; c < 16; ++c) {
    int idx = c * 256 + tid;
    int r = idx >> 6, col4 = idx & 63;
    float4 v = *(const float4*)(src_base + (size_t)r * (B_ * E_) + col4 * 4);
    unsigned p0 = (unsigned)f2bf(v.x) | ((unsigned)f2bf(v.y) << 16);
    unsigned p1 = (unsigned)f2bf(v.z) | ((unsigned)f2bf(v.w) << 16);
    *(uint2*)(tile + r * 264 + col4 * 4) = make_uint2(p0, p1);
  }
}

// ---------------- main: gate + PV for (t-tile, i-chunk, b)
__global__ __launch_bounds__(256) void attn_main_k(
    const float* __restrict__ emb, const float* __restrict__ U,
    const float* __restrict__ QC, const float* __restrict__ w0g,
    float* __restrict__ out) {
  const int tt = blockIdx.x, ic = blockIdx.y, b = blockIdx.z;
  const int t0 = tt * TT, i0 = ic * TI;
  if (i0 > t0 + TT - 1) return;

  __shared__ u16 tile[TI * 264];
  __shared__ float s_s[TT][TI];
  const int tid = threadIdx.x;
  const int wave = tid >> 6, lane = tid & 63;

  // phase 1: gate scores.  U tile (bf16) in LDS, lanes own i.
  stage_tile_bf16(U + ((size_t)i0 * B_ + b) * E_, tile, tid);
  __syncthreads();

  for (int tl = 0; tl < 4; ++tl) {
    int t = t0 + wave * 4 + tl;
    float acc0 = 0.f, acc1 = 0.f, acc2 = 0.f, acc3 = 0.f;
    if (t >= i0) {
      int row = __builtin_amdgcn_readfirstlane(t * B_ + b);
      const float* qcrow = QC + (size_t)row * E_;
      const u16* urow = tile + lane * 264;
#pragma unroll 4
      for (int g = 0; g < 32; ++g) {
        uint4 raw = *(const uint4*)(urow + g * 8);
        float4 q0 = *(const float4*)(qcrow + g * 8);
        float4 q1 = *(const float4*)(qcrow + g * 8 + 4);
        float4 z0 = *(const float4*)(w0g + g * 8);
        float4 z1 = *(const float4*)(w0g + g * 8 + 4);
        acc0 += z0.x * sigw(bflo(raw.x) + q0.x);
        acc1 += z0.y * sigw(bfhi(raw.x) + q0.y);
        acc2 += z0.z * sigw(bflo(raw.y) + q0.z);
        acc3 += z0.w * sigw(bfhi(raw.y) + q0.w);
        acc0 += z1.x * sigw(bflo(raw.z) + q1.x);
        acc1 += z1.y * sigw(bfhi(raw.z) + q1.y);
        acc2 += z1.z * sigw(bflo(raw.w) + q1.z);
        acc3 += z1.w * sigw(bfhi(raw.w) + q1.w);
      }
    }
    float s = (acc0 + acc1) + (acc2 + acc3);
    if (i0 + lane > t) s = 0.f;
    s_s[wave * 4 + tl][lane] = s;
  }
  __syncthreads();

  // phase 2: PV.  Re-stage same LDS buffer with emb tile, lanes own e.
  stage_tile_bf16(emb + ((size_t)i0 * B_ + b) * E_, tile, tid);
  __syncthreads();

  for (int tl = 0; tl < 4; ++tl) {
    int t = t0 + wave * 4 + tl;
    if (t < i0) continue;
    float4 o = make_float4(0.f, 0.f, 0.f, 0.f);
    const int nI = min(TI, t - i0 + 1);
    const float* srow = &s_s[wave * 4 + tl][0];
    for (int i = 0; i < nI; ++i) {
      float s = srow[i];
      uint2 raw = *(const uint2*)(tile + i * 264 + lane * 4);
      o.x += s * bflo(raw.x);
      o.y += s * bfhi(raw.x);
      o.z += s * bflo(raw.y);
      o.w += s * bfhi(raw.y);
    }
    float* op = out + ((size_t)t * B_ + b) * E_ + lane * 4;
    atomicAdd(op + 0, o.x);
    atomicAdd(op + 1, o.y);
    atomicAdd(op + 2, o.z);
    atomicAdd(op + 3, o.w);
  }
}

extern "C" void kernel_launch(void* const* d_in, const int* in_sizes, int n_in,
                              void* d_out, int out_size, void* d_ws, size_t ws_size,
                              hipStream_t stream) {
  const float* emb = (const float*)d_in[0];
  const float* w1  = (const float*)d_in[1];
  const float* w2  = (const float*)d_in[2];
  const float* w3  = (const float*)d_in[3];
  const float* b3  = (const float*)d_in[4];
  const float* w0  = (const float*)d_in[5];
  float* out = (float*)d_out;

  float* U  = (float*)d_ws;            // 2048x256
  float* Q2 = U + 524288;              // 2048x256
  float* QC = Q2 + 524288;             // 2048x256 (v3, then qc in-place)

  hipMemsetAsync(out, 0, (size_t)524288 * sizeof(float), stream);
  gemm3_k<<<dim3(32, 4, 3), 256, 0, stream>>>(emb, w1, w2, w3, U, Q2, QC);
  cumsum_k<<<dim3(4), 256, 0, stream>>>(Q2, QC, b3);
  attn_main_k<<<dim3(L_ / TT, L_ / TI, B_), 256, 0, stream>>>(emb, U, QC, w0, out);
}

// Round 2
// 171.367 us; speedup vs baseline: 1.2063x; 1.2063x over previous
//
#include <hip/hip_runtime.h>
#include <hip/hip_bf16.h>

#define L_  512
#define B_  4
#define E_  256
#define TT  8
#define TI  64
#define CH  16          // cumsum chunks
#define ROWS_PER_CH (L_ / CH)

typedef unsigned short u16;

#define NLOG2E (-1.44269504f)

__device__ __forceinline__ float bflo(unsigned u) { return __uint_as_float(u << 16); }
__device__ __forceinline__ float bfhi(unsigned u) { return __uint_as_float(u & 0xffff0000u); }

__device__ __forceinline__ unsigned pack_bf2(float x, float y) {
  __hip_bfloat162 h = __float22bfloat162_rn(make_float2(x, y));
  return *reinterpret_cast<unsigned*>(&h);
}

// inputs pre-scaled by -log2(e):  sig(x) = 1/(1+2^(xs))
__device__ __forceinline__ float sigs(float xs) {
  float e = __builtin_amdgcn_exp2f(xs);
  return __builtin_amdgcn_rcpf(1.0f + e);
}

// ---------------- GEMM: O[r][f] = sum_e A[r][e] * W[f][e]; z==0 output pre-scaled by -log2e
__global__ __launch_bounds__(256) void gemm3_k(
    const float* __restrict__ A,
    const float* __restrict__ w1, const float* __restrict__ w2, const float* __restrict__ w3,
    float* __restrict__ o1, float* __restrict__ o2, float* __restrict__ o3) {
  __shared__ float As[64 * 32], Ws[64 * 32];
  const int tid = threadIdx.x, tx = tid & 15, ty = tid >> 4;
  const int r0 = blockIdx.x * 64, f0 = blockIdx.y * 64, z = blockIdx.z;
  const float* W = (z == 0) ? w1 : (z == 1) ? w2 : w3;
  float* O = (z == 0) ? o1 : (z == 1) ? o2 : o3;
  float acc[4][4] = {};
  for (int kb = 0; kb < 256; kb += 32) {
    for (int j = 0; j < 2; ++j) {
      int idx = j * 256 + tid;
      int r = idx >> 3, g = idx & 7;
      float4 av = *(const float4*)(A + (size_t)(r0 + r) * E_ + kb + g * 4);
      float4 wv = *(const float4*)(W + (size_t)(f0 + r) * E_ + kb + g * 4);
      int gs = g ^ ((r >> 2) & 7);
      *(float4*)(As + r * 32 + gs * 4) = av;
      *(float4*)(Ws + r * 32 + gs * 4) = wv;
    }
    __syncthreads();
#pragma unroll
    for (int g = 0; g < 8; ++g) {
      float4 a[4], w[4];
#pragma unroll
      for (int i = 0; i < 4; ++i) {
        int r = ty * 4 + i;
        a[i] = *(const float4*)(As + r * 32 + (g ^ ((r >> 2) & 7)) * 4);
        int f = tx * 4 + i;
        w[i] = *(const float4*)(Ws + f * 32 + (g ^ ((f >> 2) & 7)) * 4);
      }
#pragma unroll
      for (int i = 0; i < 4; ++i)
#pragma unroll
        for (int j = 0; j < 4; ++j)
          acc[i][j] += a[i].x * w[j].x + a[i].y * w[j].y + a[i].z * w[j].z + a[i].w * w[j].w;
    }
    __syncthreads();
  }
  const float scl = (z == 0) ? NLOG2E : 1.0f;
#pragma unroll
  for (int i = 0; i < 4; ++i) {
    float4 v = make_float4(acc[i][0] * scl, acc[i][1] * scl, acc[i][2] * scl, acc[i][3] * scl);
    *(float4*)(O + (size_t)(r0 + ty * 4 + i) * E_ + f0 + tx * 4) = v;
  }
}

// ---------------- scan A: per-chunk column sums of v3
__global__ __launch_bounds__(256) void scanA_k(
    const float* __restrict__ v3, float* __restrict__ tot) {
  const int e = threadIdx.x, c = blockIdx.x, b = blockIdx.y;
  float s = 0.f;
  for (int l = c * ROWS_PER_CH; l < (c + 1) * ROWS_PER_CH; ++l)
    s += v3[((size_t)l * B_ + b) * E_ + e];
  tot[((size_t)c * B_ + b) * E_ + e] = s;
}

// ---------------- scan B: qc = -log2e * (q2 + b3 + prefix(v3)), written over q2
__global__ __launch_bounds__(256) void scanB_k(
    const float* __restrict__ v3, float* __restrict__ q2qc,
    const float* __restrict__ b3, const float* __restrict__ tot) {
  const int e = threadIdx.x, c = blockIdx.x, b = blockIdx.y;
  float run = 0.f;
  for (int cc = 0; cc < c; ++cc)
    run += tot[((size_t)cc * B_ + b) * E_ + e];
  const float bb = b3[e];
  for (int l = c * ROWS_PER_CH; l < (c + 1) * ROWS_PER_CH; ++l) {
    size_t o = ((size_t)l * B_ + b) * E_ + e;
    run += v3[o];
    q2qc[o] = NLOG2E * (q2qc[o] + bb + run);
  }
}

// ---------------- stage 64 rows x 256 cols fp32 -> bf16 LDS tile (pitch 264)
__device__ __forceinline__ void stage_tile_bf16(const float* __restrict__ src_base,
                                                u16* tile, int tid) {
#pragma unroll
  for (int c = 0; c < 16; ++c) {
    int idx = c * 256 + tid;
    int r = idx >> 6, col4 = idx & 63;
    float4 v = *(const float4*)(src_base + (size_t)r * (B_ * E_) + col4 * 4);
    unsigned p0 = pack_bf2(v.x, v.y);
    unsigned p1 = pack_bf2(v.z, v.w);
    *(uint2*)(tile + r * 264 + col4 * 4) = make_uint2(p0, p1);
  }
}

// ---------------- main: gate + PV for (t-tile of 8, i-chunk of 64, b)
__global__ __launch_bounds__(256) void attn_main_k(
    const float* __restrict__ emb, const float* __restrict__ U,
    const float* __restrict__ QC, const float* __restrict__ w0g,
    float* __restrict__ out) {
  const int tt = blockIdx.x, ic = blockIdx.y, b = blockIdx.z;
  const int t0 = tt * TT, i0 = ic * TI;
  if (i0 > t0 + TT - 1) return;

  __shared__ u16 tile[TI * 264];
  __shared__ float s_s[TT][TI];
  const int tid = threadIdx.x;
  const int wave = tid >> 6, lane = tid & 63;

  // phase 1: gate scores.  U tile (bf16, pre-scaled by -log2e) in LDS, lanes own i.
  stage_tile_bf16(U + ((size_t)i0 * B_ + b) * E_, tile, tid);
  __syncthreads();

#pragma unroll
  for (int tl = 0; tl < 2; ++tl) {
    int t = t0 + wave * 2 + tl;
    float acc0 = 0.f, acc1 = 0.f, acc2 = 0.f, acc3 = 0.f;
    if (t >= i0) {
      int row = __builtin_amdgcn_readfirstlane(t * B_ + b);
      const float* qcrow = QC + (size_t)row * E_;
      const u16* urow = tile + lane * 264;
#pragma unroll 4
      for (int g = 0; g < 32; ++g) {
        uint4 raw = *(const uint4*)(urow + g * 8);
        float4 q0 = *(const float4*)(qcrow + g * 8);
        float4 q1 = *(const float4*)(qcrow + g * 8 + 4);
        float4 z0 = *(const float4*)(w0g + g * 8);
        float4 z1 = *(const float4*)(w0g + g * 8 + 4);
        acc0 += z0.x * sigs(bflo(raw.x) + q0.x);
        acc1 += z0.y * sigs(bfhi(raw.x) + q0.y);
        acc2 += z0.z * sigs(bflo(raw.y) + q0.z);
        acc3 += z0.w * sigs(bfhi(raw.y) + q0.w);
        acc0 += z1.x * sigs(bflo(raw.z) + q1.x);
        acc1 += z1.y * sigs(bfhi(raw.z) + q1.y);
        acc2 += z1.z * sigs(bflo(raw.w) + q1.z);
        acc3 += z1.w * sigs(bfhi(raw.w) + q1.w);
      }
    }
    float s = (acc0 + acc1) + (acc2 + acc3);
    if (i0 + lane > t) s = 0.f;
    s_s[wave * 2 + tl][lane] = s;
  }
  __syncthreads();

  // phase 2: PV.  Re-stage same LDS buffer with emb tile, lanes own e.
  stage_tile_bf16(emb + ((size_t)i0 * B_ + b) * E_, tile, tid);
  __syncthreads();

#pragma unroll
  for (int tl = 0; tl < 2; ++tl) {
    int t = t0 + wave * 2 + tl;
    if (t < i0) continue;
    float4 o = make_float4(0.f, 0.f, 0.f, 0.f);
    const int nI = min(TI, t - i0 + 1);
    const float* srow = &s_s[wave * 2 + tl][0];
    for (int i = 0; i < nI; ++i) {
      float s = srow[i];
      uint2 raw = *(const uint2*)(tile + i * 264 + lane * 4);
      o.x += s * bflo(raw.x);
      o.y += s * bfhi(raw.x);
      o.z += s * bflo(raw.y);
      o.w += s * bfhi(raw.y);
    }
    float* op = out + ((size_t)t * B_ + b) * E_ + lane * 4;
    atomicAdd(op + 0, o.x);
    atomicAdd(op + 1, o.y);
    atomicAdd(op + 2, o.z);
    atomicAdd(op + 3, o.w);
  }
}

extern "C" void kernel_launch(void* const* d_in, const int* in_sizes, int n_in,
                              void* d_out, int out_size, void* d_ws, size_t ws_size,
                              hipStream_t stream) {
  const float* emb = (const float*)d_in[0];
  const float* w1  = (const float*)d_in[1];
  const float* w2  = (const float*)d_in[2];
  const float* w3  = (const float*)d_in[3];
  const float* b3  = (const float*)d_in[4];
  const float* w0  = (const float*)d_in[5];
  float* out = (float*)d_out;

  float* U   = (float*)d_ws;           // 2048x256, pre-scaled by -log2e
  float* Q2  = U + 524288;             // 2048x256 -> becomes QC (scaled) in scanB
  float* V3  = Q2 + 524288;            // 2048x256
  float* TOT = V3 + 524288;            // 16x4x256 chunk sums

  hipMemsetAsync(out, 0, (size_t)524288 * sizeof(float), stream);
  gemm3_k<<<dim3(32, 4, 3), 256, 0, stream>>>(emb, w1, w2, w3, U, Q2, V3);
  scanA_k<<<dim3(CH, B_), 256, 0, stream>>>(V3, TOT);
  scanB_k<<<dim3(CH, B_), 256, 0, stream>>>(V3, Q2, b3, TOT);
  attn_main_k<<<dim3(L_ / TT, L_ / TI, B_), 256, 0, stream>>>(emb, U, Q2, w0, out);
}

// Round 3
// 152.562 us; speedup vs baseline: 1.3550x; 1.1233x over previous
//
#include <hip/hip_runtime.h>
#include <hip/hip_bf16.h>

#define L_  512
#define B_  4
#define E_  256
#define TT  8
#define TI  64

typedef unsigned short u16;
#define NLOG2E (-1.44269504f)

__device__ __forceinline__ float bflo(unsigned u) { return __uint_as_float(u << 16); }
__device__ __forceinline__ float bfhi(unsigned u) { return __uint_as_float(u & 0xffff0000u); }

__device__ __forceinline__ unsigned pack_bf2(float x, float y) {
  __hip_bfloat162 h = __float22bfloat162_rn(make_float2(x, y));
  return *reinterpret_cast<unsigned*>(&h);
}

// inputs pre-scaled by -log2(e):  sig(x) = 1/(1+2^(xs))
__device__ __forceinline__ float sigs(float xs) {
  float e = __builtin_amdgcn_exp2f(xs);
  return __builtin_amdgcn_rcpf(1.0f + e);
}

// ---------------- GEMM: O[r][f] = sum_e A[r][e] * W[f][e]; z==0 output pre-scaled by -log2e
__global__ __launch_bounds__(256) void gemm3_k(
    const float* __restrict__ A,
    const float* __restrict__ w1, const float* __restrict__ w2, const float* __restrict__ w3,
    float* __restrict__ o1, float* __restrict__ o2, float* __restrict__ o3) {
  __shared__ float As[64 * 32], Ws[64 * 32];
  const int tid = threadIdx.x, tx = tid & 15, ty = tid >> 4;
  const int r0 = blockIdx.x * 64, f0 = blockIdx.y * 64, z = blockIdx.z;
  const float* W = (z == 0) ? w1 : (z == 1) ? w2 : w3;
  float* O = (z == 0) ? o1 : (z == 1) ? o2 : o3;
  float acc[4][4] = {};
  for (int kb = 0; kb < 256; kb += 32) {
    for (int j = 0; j < 2; ++j) {
      int idx = j * 256 + tid;
      int r = idx >> 3, g = idx & 7;
      float4 av = *(const float4*)(A + (size_t)(r0 + r) * E_ + kb + g * 4);
      float4 wv = *(const float4*)(W + (size_t)(f0 + r) * E_ + kb + g * 4);
      int gs = g ^ ((r >> 2) & 7);
      *(float4*)(As + r * 32 + gs * 4) = av;
      *(float4*)(Ws + r * 32 + gs * 4) = wv;
    }
    __syncthreads();
#pragma unroll
    for (int g = 0; g < 8; ++g) {
      float4 a[4], w[4];
#pragma unroll
      for (int i = 0; i < 4; ++i) {
        int r = ty * 4 + i;
        a[i] = *(const float4*)(As + r * 32 + (g ^ ((r >> 2) & 7)) * 4);
        int f = tx * 4 + i;
        w[i] = *(const float4*)(Ws + f * 32 + (g ^ ((f >> 2) & 7)) * 4);
      }
#pragma unroll
      for (int i = 0; i < 4; ++i)
#pragma unroll
        for (int j = 0; j < 4; ++j)
          acc[i][j] += a[i].x * w[j].x + a[i].y * w[j].y + a[i].z * w[j].z + a[i].w * w[j].w;
    }
    __syncthreads();
  }
  const float scl = (z == 0) ? NLOG2E : 1.0f;
#pragma unroll
  for (int i = 0; i < 4; ++i) {
    float4 v = make_float4(acc[i][0] * scl, acc[i][1] * scl, acc[i][2] * scl, acc[i][3] * scl);
    *(float4*)(O + (size_t)(r0 + ty * 4 + i) * E_ + f0 + tx * 4) = v;
  }
}

// ---------------- single-kernel chunked scan:
// qc[l,C] = NLOG2E * (q2[l,C] + b3[e] + prefix_incl(v3)[l,C]);  C = b*256+e in [0,1024)
__global__ __launch_bounds__(256) void scan_k(
    const float* __restrict__ v3, float* __restrict__ q2qc, const float* __restrict__ b3g) {
  const int bc = blockIdx.x;            // 64 blocks x 16 cols
  const int cg = threadIdx.x & 3;       // float4 col group
  const int rk = threadIdx.x >> 2;      // 0..63 -> rows rk*8 .. rk*8+7
  const int C = bc * 16 + cg * 4;
  __shared__ float4 s_p[64][4];
  float4 part = {0.f, 0.f, 0.f, 0.f};
  for (int l = rk * 8; l < rk * 8 + 8; ++l) {
    float4 v = *(const float4*)(v3 + (size_t)l * 1024 + C);
    part.x += v.x; part.y += v.y; part.z += v.z; part.w += v.w;
  }
  s_p[rk][cg] = part;
  __syncthreads();
  float4 run = {0.f, 0.f, 0.f, 0.f};
  for (int k = 0; k < rk; ++k) {
    float4 p = s_p[k][cg];
    run.x += p.x; run.y += p.y; run.z += p.z; run.w += p.w;
  }
  const int e = C & 255;
  float4 bb = *(const float4*)(b3g + e);
  for (int l = rk * 8; l < rk * 8 + 8; ++l) {
    size_t o = (size_t)l * 1024 + C;
    float4 v = *(const float4*)(v3 + o);
    run.x += v.x; run.y += v.y; run.z += v.z; run.w += v.w;
    float4 q = *(const float4*)(q2qc + o);
    float4 r;
    r.x = NLOG2E * (q.x + bb.x + run.x);
    r.y = NLOG2E * (q.y + bb.y + run.y);
    r.z = NLOG2E * (q.z + bb.z + run.z);
    r.w = NLOG2E * (q.w + bb.w + run.w);
    *(float4*)(q2qc + o) = r;
  }
}

// ---------------- main: gate + PV for (t-tile of 8, i-chunk of 64, b)
__global__ __launch_bounds__(256) void attn_main_k(
    const float* __restrict__ emb, const float* __restrict__ U,
    const float* __restrict__ QC, const float* __restrict__ w0g,
    float* __restrict__ out) {
  const int tt = blockIdx.x, ic = blockIdx.y, b = blockIdx.z;
  const int t0 = tt * TT, i0 = ic * TI;
  if (i0 > t0) return;   // active blocks always have full t-range >= i0

  __shared__ u16 tile[TI * 264];
  __shared__ float s_s[TT][TI];
  const int tid = threadIdx.x, wave = tid >> 6, lane = tid & 63;

  // stage U tile (bf16, pre-scaled): wave w stages rows c*4+w, full-row coalesced
  {
    const float* src = U + ((size_t)i0 * B_ + b) * E_ + lane * 4;
#pragma unroll
    for (int c = 0; c < 16; ++c) {
      int r = c * 4 + wave;
      float4 v = *(const float4*)(src + (size_t)r * (B_ * E_));
      *(uint2*)(tile + r * 264 + lane * 4) =
          make_uint2(pack_bf2(v.x, v.y), pack_bf2(v.z, v.w));
    }
  }
  __syncthreads();

  const int tA = t0 + wave * 2, tB = tA + 1;
  {
    int rA = __builtin_amdgcn_readfirstlane(tA * B_ + b);
    int rB = __builtin_amdgcn_readfirstlane(tB * B_ + b);
    const float* qA = QC + (size_t)rA * E_;
    const float* qB = QC + (size_t)rB * E_;
    const u16* urow = tile + lane * 264;
    float a0 = 0.f, a1 = 0.f, a2 = 0.f, a3 = 0.f;
    float c0 = 0.f, c1 = 0.f, c2 = 0.f, c3 = 0.f;
#pragma unroll 4
    for (int g = 0; g < 32; ++g) {
      uint4 raw = *(const uint4*)(urow + g * 8);
      float4 z0 = *(const float4*)(w0g + g * 8);
      float4 z1 = *(const float4*)(w0g + g * 8 + 4);
      float4 qa0 = *(const float4*)(qA + g * 8);
      float4 qa1 = *(const float4*)(qA + g * 8 + 4);
      float4 qb0 = *(const float4*)(qB + g * 8);
      float4 qb1 = *(const float4*)(qB + g * 8 + 4);
      float u0 = bflo(raw.x), u1 = bfhi(raw.x), u2 = bflo(raw.y), u3 = bfhi(raw.y);
      float u4 = bflo(raw.z), u5 = bfhi(raw.z), u6 = bflo(raw.w), u7 = bfhi(raw.w);
      a0 += z0.x * sigs(u0 + qa0.x); a1 += z0.y * sigs(u1 + qa0.y);
      a2 += z0.z * sigs(u2 + qa0.z); a3 += z0.w * sigs(u3 + qa0.w);
      a0 += z1.x * sigs(u4 + qa1.x); a1 += z1.y * sigs(u5 + qa1.y);
      a2 += z1.z * sigs(u6 + qa1.z); a3 += z1.w * sigs(u7 + qa1.w);
      c0 += z0.x * sigs(u0 + qb0.x); c1 += z0.y * sigs(u1 + qb0.y);
      c2 += z0.z * sigs(u2 + qb0.z); c3 += z0.w * sigs(u3 + qb0.w);
      c0 += z1.x * sigs(u4 + qb1.x); c1 += z1.y * sigs(u5 + qb1.y);
      c2 += z1.z * sigs(u6 + qb1.z); c3 += z1.w * sigs(u7 + qb1.w);
    }
    float sA = (a0 + a1) + (a2 + a3), sB = (c0 + c1) + (c2 + c3);
    int i = i0 + lane;
    s_s[wave * 2][lane]     = (i <= tA) ? sA : 0.f;
    s_s[wave * 2 + 1][lane] = (i <= tB) ? sB : 0.f;
  }
  __syncthreads();

  // PV: emb read direct from global (fp32, lane owns e -> coalesced row reads)
  {
    const float* embp = emb + ((size_t)i0 * B_ + b) * E_ + lane * 4;
    const float* sAv = s_s[wave * 2];
    const float* sBv = s_s[wave * 2 + 1];
    int nI = min(TI, tB - i0 + 1);
    nI = (nI + 3) & ~3;
    float4 o0 = {0.f, 0.f, 0.f, 0.f}, o1 = {0.f, 0.f, 0.f, 0.f};
    for (int i = 0; i < nI; i += 4) {
#pragma unroll
      for (int k = 0; k < 4; ++k) {
        float4 r = *(const float4*)(embp + (size_t)(i + k) * (B_ * E_));
        float s0 = sAv[i + k], s1 = sBv[i + k];
        o0.x += s0 * r.x; o0.y += s0 * r.y; o0.z += s0 * r.z; o0.w += s0 * r.w;
        o1.x += s1 * r.x; o1.y += s1 * r.y; o1.z += s1 * r.z; o1.w += s1 * r.w;
      }
    }
    float* opA = out + ((size_t)tA * B_ + b) * E_ + lane * 4;
    float* opB = out + ((size_t)tB * B_ + b) * E_ + lane * 4;
    atomicAdd(opA + 0, o0.x); atomicAdd(opA + 1, o0.y);
    atomicAdd(opA + 2, o0.z); atomicAdd(opA + 3, o0.w);
    atomicAdd(opB + 0, o1.x); atomicAdd(opB + 1, o1.y);
    atomicAdd(opB + 2, o1.z); atomicAdd(opB + 3, o1.w);
  }
}

extern "C" void kernel_launch(void* const* d_in, const int* in_sizes, int n_in,
                              void* d_out, int out_size, void* d_ws, size_t ws_size,
                              hipStream_t stream) {
  const float* emb = (const float*)d_in[0];
  const float* w1  = (const float*)d_in[1];
  const float* w2  = (const float*)d_in[2];
  const float* w3  = (const float*)d_in[3];
  const float* b3  = (const float*)d_in[4];
  const float* w0  = (const float*)d_in[5];
  float* out = (float*)d_out;

  float* U  = (float*)d_ws;            // 2048x256, pre-scaled by -log2e
  float* Q2 = U + 524288;              // 2048x256 -> becomes QC (scaled) in scan_k
  float* V3 = Q2 + 524288;             // 2048x256

  hipMemsetAsync(out, 0, (size_t)524288 * sizeof(float), stream);
  gemm3_k<<<dim3(32, 4, 3), 256, 0, stream>>>(emb, w1, w2, w3, U, Q2, V3);
  scan_k<<<dim3(64), 256, 0, stream>>>(V3, Q2, b3);
  attn_main_k<<<dim3(L_ / TT, L_ / TI, B_), 256, 0, stream>>>(emb, U, Q2, w0, out);
}